// Round 10
// baseline (308.617 us; speedup 1.0000x reference)
//
#include <hip/hip_runtime.h>

// ---------------------------------------------------------------------------
// Fused MHA block on gfx950, fp16 MFMA pipeline.
//   qkv GEMM (16384x2304x768, A=fp32 fused-converted) -> per-head flash
//   attention (192 x 1024x1024x64) -> proj GEMM (16384x768x768)
// GEMMs (r9 measured-best, unchanged): 128x256 tiles, 8 waves, BK=32,
//   2-phase loop, gld_lds B (+A cvt ds_write for qkv), XCD swizzle.
//   Ledger: (256,{4,5}) regress; A-LDS-bypass regress; 8-phase/T2-on-GEMM/
//   T5/T13 all null; qkv invariant ~120us across 5 structures.
// Attention (REWRITTEN for occupancy): attn was VGPR-bound at 2 waves/SIMD
//   (~200 VGPR: sf64+of64+pdw32+qb32+pf16). Now 32 q-rows/wave (128-q
//   blocks, grid 1536): core regs halve (~140 total) -> 3 waves/SIMD,
//   12 waves/CU (3 blocks x 32KB LDS = 96KB). K/V staged via global_load_lds
//   into linear [64][64] tiles with T2 both-sides XOR swizzle
//   (pre-swizzled per-lane GLOBAL source, same XOR on ds_read; rule #21),
//   eliminating pf regs + per-iter ds_writes. Same math order per q.
// ---------------------------------------------------------------------------

typedef _Float16 half8 __attribute__((ext_vector_type(8)));
typedef _Float16 half4 __attribute__((ext_vector_type(4)));
typedef __fp16   fp16x2 __attribute__((ext_vector_type(2)));
typedef float    f32x4  __attribute__((ext_vector_type(4)));
typedef float    f32x16 __attribute__((ext_vector_type(16)));
typedef unsigned int u32x4 __attribute__((ext_vector_type(4)));

#define DI __device__ __forceinline__

constexpr int   BATCH  = 16;
constexpr int   SEQ    = 1024;
constexpr int   DM     = 768;
constexpr int   NH     = 12;
constexpr int   HD     = 64;
constexpr float SCALE  = 0.125f;          // 1/sqrt(64), folded into Q epilogue
constexpr float LOG2E  = 1.4426950408889634f;

DI void copy16(_Float16* dst, const _Float16* src) {
  *(u32x4*)dst = *(const u32x4*)src;
}

DI int pack_rtz(float a, float b) {
  union { fp16x2 h; int i; } u;
  u.h = __builtin_amdgcn_cvt_pkrtz(a, b);
  return u.i;
}

// async global->LDS, 16 B per lane; lds base must be wave-uniform,
// HW writes lane l at lds + l*16.  GLOBAL source address is per-lane.
DI void gld16(const _Float16* g, _Float16* l) {
  __builtin_amdgcn_global_load_lds(
      (const __attribute__((address_space(1))) void*)g,
      (__attribute__((address_space(3))) void*)l, 16, 0, 0);
}

// ---------------------------------------------------------------------------
// converts (weights only; x conversion is fused into gemm_qkv)
// ---------------------------------------------------------------------------
// both weight transposes in one launch: wt[n*K+k] = w[k*N+n]
__global__ void cvt_wt2_kernel(const float* __restrict__ wq,
                               _Float16* __restrict__ wqT,
                               const float* __restrict__ wp,
                               _Float16* __restrict__ wpT) {
  __shared__ float tile[32][33];
  const int by = blockIdx.y;
  const float* w; _Float16* wt; int N, nb;
  if (by < 72) { w = wq; wt = wqT; N = 2304; nb = by * 32; }
  else         { w = wp; wt = wpT; N = 768;  nb = (by - 72) * 32; }
  const int K = 768;
  int kb = blockIdx.x * 32;
  int tx = threadIdx.x & 31, ty = threadIdx.x >> 5;   // ty 0..7
#pragma unroll
  for (int i = 0; i < 32; i += 8)
    tile[ty + i][tx] = w[(size_t)(kb + ty + i) * N + nb + tx];
  __syncthreads();
#pragma unroll
  for (int i = 0; i < 32; i += 8)
    wt[(size_t)(nb + ty + i) * K + kb + tx] = (_Float16)tile[tx][ty + i];
}

// ---------------------------------------------------------------------------
// GEMM1: qkv = x[16384x768 fp32] @ wqkvT^T + bias, scatter epilogue into
//   Q[bh][n][d] (prescaled by 0.125), K[bh][n][d], VT[bh][d][n]  (fp16)
// 128x256 tile, 512 thr (8 waves 2x4). A: fp32->regs->cvt->ds_write.
// B: global_load_lds. LDS/buf: As 4096 h + Bs 8192 h = 24 KB; 2 bufs.
// ---------------------------------------------------------------------------
__launch_bounds__(512, 3)
__global__ void gemm_qkv_kernel(const float* __restrict__ X,
                                const _Float16* __restrict__ Bt,
                                const float* __restrict__ bias,
                                _Float16* __restrict__ Qo,
                                _Float16* __restrict__ Ko,
                                _Float16* __restrict__ VTo) {
  __shared__ _Float16 sh[24576];       // 2 bufs x 12288 halves (49152 B)
  _Float16* Cs = sh;                   // epilogue alias (64*264 = 16896 halves)
  const int tid  = threadIdx.x;
  // XCD swizzle: all 9 column tiles of one m0 land on one XCD (lin&7)
  const int lin  = blockIdx.x;         // 1152 blocks, 1152%8==0 bijective
  const int xcd  = lin & 7, j = lin >> 3;
  const int ct   = j % 9;              // 0..8 col tiles of 256
  const int m0   = ((j / 9) * 8 + xcd) * 128;
  const int n0   = ct * 256;
  const int w    = tid >> 6, lane = tid & 63;
  const int quad = lane >> 4, l15 = lane & 15;
  const int wr   = w >> 2, wc = w & 3; // 2 row-waves x 4 col-waves

  f32x4 acc[4][4] = {};

  // ---- A staging geometry (512 thr, one granule each): row tid>>2, seg tid&3
  const int rA = tid >> 2, sA = tid & 3;
  const float* gaA = X + (size_t)(m0 + rA) * 768 + sA * 8;
  const int so = rA * 32 + sA * 8;     // linear [128][32] dest (halves)

  // ---- B staging (gld_lds): granule g = w*128 + c*64 + lane (c = call 0/1)
  //      row g>>2 (0..255), seg g&3; dest = g*8 halves.
  const _Float16* gbB = Bt + (size_t)(n0 + ((w * 128 + lane) >> 2)) * 768
                           + (lane & 3) * 8;
  const int ldst = w * 1024;           // B dest halves, call 0 (call 1: +512)

  auto CVT_WRITE = [&](float4 a0, float4 a1, _Float16* As) {
    half8 h0;
    h0[0] = (_Float16)a0.x; h0[1] = (_Float16)a0.y;
    h0[2] = (_Float16)a0.z; h0[3] = (_Float16)a0.w;
    h0[4] = (_Float16)a1.x; h0[5] = (_Float16)a1.y;
    h0[6] = (_Float16)a1.z; h0[7] = (_Float16)a1.w;
    *(half8*)(As + so) = h0;
  };

  // prologue: tile 0 -> buf 0  (As at 0, Bs at 4096)
  {
    float4 a0 = *(const float4*)(gaA);
    float4 a1 = *(const float4*)(gaA + 4);
    CVT_WRITE(a0, a1, sh);
    gld16(gbB,            sh + 4096 + ldst);
    gld16(gbB + 16 * 768, sh + 4096 + ldst + 512);
  }

  for (int kt = 0; kt < 24; ++kt) {
    __syncthreads();                   // drains vm (B) + lgkm (A writes)
    float4 a0, a1;
    if (kt < 23) {                     // prefetch next tile
      const int k0 = (kt + 1) * 32;
      a0 = *(const float4*)(gaA + k0);
      a1 = *(const float4*)(gaA + k0 + 4);
      _Float16* Bsn = sh + ((kt + 1) & 1) * 12288 + 4096;
      gld16(gbB + k0,            Bsn + ldst);
      gld16(gbB + k0 + 16 * 768, Bsn + ldst + 512);
    }

    const _Float16* As = sh + (kt & 1) * 12288;
    const _Float16* Bs = As + 4096;

    half8 af[4], bf[4];
#pragma unroll
    for (int mi = 0; mi < 4; mi++)
      af[mi] = *(const half8*)&As[(wr * 64 + mi * 16 + l15) * 32 + quad * 8];
#pragma unroll
    for (int ni = 0; ni < 4; ni++)
      bf[ni] = *(const half8*)&Bs[(wc * 64 + ni * 16 + l15) * 32 + quad * 8];
#pragma unroll
    for (int mi = 0; mi < 4; mi++)
#pragma unroll
      for (int ni = 0; ni < 4; ni++)
        acc[mi][ni] = __builtin_amdgcn_mfma_f32_16x16x32_f16(
            af[mi], bf[ni], acc[mi][ni], 0, 0, 0);

    if (kt < 23)                       // stage converted A into other buf
      CVT_WRITE(a0, a1, sh + ((kt + 1) & 1) * 12288);
  }
  __syncthreads();

  const int   sec    = ct / 3;         // 0=Q 1=K 2=V
  const int   h0     = (ct % 3) * 4;   // 4 heads per 256-col tile
  const float oscale = (sec == 0) ? SCALE : 1.0f;
  float bcol[4];
#pragma unroll
  for (int ni = 0; ni < 4; ni++)
    bcol[ni] = bias[n0 + wc * 64 + ni * 16 + l15];

  const int b     = m0 >> 10;
  const int nrow0 = m0 & 1023;

  // two passes of 64 rows each through Cs[64][264]
#pragma unroll
  for (int p = 0; p < 2; ++p) {
    if (p) __syncthreads();            // pass-0 reads done before overwrite
    if (wr == p) {
#pragma unroll
      for (int mi = 0; mi < 4; mi++)
#pragma unroll
        for (int ni = 0; ni < 4; ni++) {
          int col = wc * 64 + ni * 16 + l15;
          int row = mi * 16 + quad * 4;
#pragma unroll
          for (int r = 0; r < 4; r++)
            Cs[(row + r) * 264 + col] =
                (_Float16)((acc[mi][ni][r] + bcol[ni]) * oscale);
        }
    }
    __syncthreads();

    if (sec < 2) {
      _Float16* dst = (sec == 0) ? Qo : Ko;
      int row = tid >> 3, seg = tid & 7;     // 64 rows x 8 segs of 32
      int hl = seg >> 1, off32 = (seg & 1) * 32;
      _Float16* g = dst +
          ((size_t)((b * NH + h0 + hl) * SEQ + nrow0 + p * 64 + row)) * HD + off32;
      const _Float16* s = &Cs[row * 264 + hl * 64 + off32];
      copy16(g, s);
      copy16(g + 8, s + 8);
      copy16(g + 16, s + 16);
      copy16(g + 24, s + 24);
    } else {
      int c = tid & 255, rh = tid >> 8;      // col, row half (32 rows each)
      int hl = c >> 6, d = c & 63;
      _Float16 tmp[32];
#pragma unroll
      for (int jj = 0; jj < 32; jj++) tmp[jj] = Cs[(rh * 32 + jj) * 264 + c];
      _Float16* g = VTo + ((size_t)((b * NH + h0 + hl) * HD + d)) * SEQ
                        + nrow0 + p * 64 + rh * 32;
#pragma unroll
      for (int jj = 0; jj < 4; jj++)
        copy16(g + jj * 8, (const _Float16*)&tmp[jj * 8]);
    }
  }
}

// ---------------------------------------------------------------------------
// Flash attention, transposed: one wg = (bh, 128-q tile), 4 waves x 32 q.
// S^T = K Q^T (32x32x16 MFMA), P^T in registers via half-swap shuffles,
// O^T = V^T P^T.  K-tile 64, double-buffered gld_lds staging with T2
// both-sides XOR swizzle (linear [64][64] tiles; stored 16B-slot s at row r
// holds logical slot s^(r&7); source pre-swizzled, reads XOR the same).
// 32 q/wave halves sf/of/pdw/qb VGPRs -> target 3 waves/SIMD.
// ---------------------------------------------------------------------------
__launch_bounds__(256, 3)
__global__ void attn_kernel(const _Float16* __restrict__ Q,
                            const _Float16* __restrict__ K,
                            const _Float16* __restrict__ VT,
                            _Float16* __restrict__ Oh) {
  __shared__ _Float16 smem[2][2][4096];  // [buf][K/V][64][64] swizzled, 32 KB
  _Float16* OLds = &smem[0][0][0];       // epilogue alias: 128 q x 64 d (16 KB)

  const int tid = threadIdx.x;
  const int i   = blockIdx.x;            // 1536 blocks
  const int xcd = i & 7, j = i >> 3;
  const int bh  = xcd * 24 + (j >> 3);   // 8 q-blocks of one bh share an XCD
  const int q0  = (j & 7) * 128;
  const int b   = bh / NH, hh = bh - b * NH;
  const int w   = tid >> 6, lane = tid & 63;
  const int l31 = lane & 31, h = lane >> 5;

  const _Float16* Qg = Q  + (size_t)bh * SEQ * HD;
  const _Float16* Kg = K  + (size_t)bh * SEQ * HD;
  const _Float16* Vg = VT + (size_t)bh * HD * SEQ;

  // persistent Q B-frag: one 32-q N-frag per wave
  half8 qb[4];
  {
    const _Float16* qrow = Qg + (size_t)(q0 + w * 32 + l31) * HD + h * 8;
#pragma unroll
    for (int s = 0; s < 4; s++) qb[s] = *(const half8*)(qrow + s * 16);
  }

  // staging: granule g = c*256 + tid -> tile row g>>3, 16B slot g&7.
  // linear dest; source slot = (g&7)^(row&7)  (row&7 == lane>>3).
  const int rS  = tid >> 3;                            // row (c=0); c=1: +32
  const int csw = ((lane & 7) ^ (lane >> 3)) << 3;     // swizzled col (halves)
  const _Float16* srcK = Kg + rS * HD + csw;
  const _Float16* srcV = Vg + (size_t)rS * SEQ + csw;

  auto STAGE = [&](int buf, int kt) {
    _Float16* base = &smem[0][0][0] + buf * 8192;
#pragma unroll
    for (int c = 0; c < 2; c++) {
      gld16(srcK + (kt * 64 + c * 32) * HD, base + c * 2048 + w * 512);
      gld16(srcV + kt * 64 + c * 32 * SEQ, base + 4096 + c * 2048 + w * 512);
    }
  };

  f32x16 of[2];
#pragma unroll
  for (int D = 0; D < 2; D++)
#pragma unroll
    for (int r = 0; r < 16; r++) of[D][r] = 0.f;
  float m_ = -1e30f, l_ = 0.f;

  const int cs0 = (l31 & 7) << 3;        // read-side row-XOR (rows l31, 32+l31)

  STAGE(0, 0);

  for (int kt = 0; kt < 16; ++kt) {
    __syncthreads();                     // vm drain: tile kt resident
    if (kt < 15) STAGE((kt + 1) & 1, kt + 1);
    const _Float16* Ks = &smem[kt & 1][0][0];
    const _Float16* Vs = &smem[kt & 1][1][0];

    // S^T = K Q^T : 2 m-frags (64 keys) x 1 n-frag (32 q)
    f32x16 sf[2];
#pragma unroll
    for (int r = 0; r < 16; r++) { sf[0][r] = 0.f; sf[1][r] = 0.f; }
#pragma unroll
    for (int s = 0; s < 4; s++) {
      const int cc = (s * 16 + h * 8) ^ cs0;
      half8 ka0 = *(const half8*)&Ks[l31 * 64 + cc];
      half8 ka1 = *(const half8*)&Ks[(32 + l31) * 64 + cc];
      sf[0] = __builtin_amdgcn_mfma_f32_32x32x16_f16(ka0, qb[s], sf[0], 0, 0, 0);
      sf[1] = __builtin_amdgcn_mfma_f32_32x32x16_f16(ka1, qb[s], sf[1], 0, 0, 0);
    }

    // online softmax; stats per q = per lane (col of S^T)
    float tmax = -1e30f;
#pragma unroll
    for (int r = 0; r < 16; r++)
      tmax = fmaxf(tmax, fmaxf(sf[0][r], sf[1][r]));
    tmax = fmaxf(tmax, __shfl_xor(tmax, 32, 64));
    float mnew  = fmaxf(m_, tmax);
    float alpha = __builtin_amdgcn_exp2f((m_ - mnew) * LOG2E);
    m_ = mnew;
    float c1 = mnew * LOG2E, tsum = 0.f;

    int pdw[2][8];
#pragma unroll
    for (int M = 0; M < 2; M++) {
#pragma unroll
      for (int r = 0; r < 16; r++) {
        float p = __builtin_amdgcn_exp2f(sf[M][r] * LOG2E - c1);
        sf[M][r] = p;
        tsum += p;
      }
#pragma unroll
      for (int u = 0; u < 8; u++)
        pdw[M][u] = pack_rtz(sf[M][2 * u], sf[M][2 * u + 1]);
    }
    tsum += __shfl_xor(tsum, 32, 64);
    l_ = l_ * alpha + tsum;
#pragma unroll
    for (int D = 0; D < 2; D++)
#pragma unroll
      for (int r = 0; r < 16; r++) of[D][r] *= alpha;

    // O^T += V^T P^T ; P^T B-frags from pdw via lane^32 half-swap
#pragma unroll
    for (int t = 0; t < 4; ++t) {
      const int M = t >> 1, s2 = (t & 1) * 4;
      const int cc = (t * 16 + h * 8) ^ cs0;
      half8 va0 = *(const half8*)&Vs[l31 * 64 + cc];
      half8 va1 = *(const half8*)&Vs[(32 + l31) * 64 + cc];
      int a0 = pdw[M][s2 + 0], a1 = pdw[M][s2 + 1];
      int a2 = pdw[M][s2 + 2], a3 = pdw[M][s2 + 3];
      int e0 = h ? a0 : a2, e1 = h ? a1 : a3;
      int r0 = __shfl_xor(e0, 32, 64), r1 = __shfl_xor(e1, 32, 64);
      union { u32x4 u; half8 hv; } bb;
      bb.u[0] = h ? r0 : a0; bb.u[1] = h ? r1 : a1;
      bb.u[2] = h ? a2 : r0; bb.u[3] = h ? a3 : r1;
      of[0] = __builtin_amdgcn_mfma_f32_32x32x16_f16(va0, bb.hv, of[0], 0, 0, 0);
      of[1] = __builtin_amdgcn_mfma_f32_32x32x16_f16(va1, bb.hv, of[1], 0, 0, 0);
    }
  }

  // epilogue: normalize, transpose O^T -> O through LDS (XOR-swizzled),
  // coalesced 16B stores
  __syncthreads();                       // staging buffers done
  float inv = 1.0f / l_;
  int* OW = (int*)OLds;
  const int q_local = w * 32 + l31;
  const int qs = (q_local & 7) << 2;     // int-index XOR
#pragma unroll
  for (int D = 0; D < 2; D++)
#pragma unroll
    for (int u = 0; u < 8; u++) {
      int v = pack_rtz(of[D][2 * u] * inv, of[D][2 * u + 1] * inv);
      int dwi = 16 * D + 4 * (u >> 1) + (u & 1) + 2 * h;
      OW[q_local * 32 + (dwi ^ qs)] = v;
    }
  __syncthreads();
#pragma unroll
  for (int p = 0; p < 4; p++) {
    int q = p * 32 + (tid >> 3), c = tid & 7;
    *(u32x4*)(Oh + (size_t)(b * SEQ + q0 + q) * DM + hh * HD + c * 8) =
        *(const u32x4*)&OLds[q * 64 + ((c ^ (q & 7)) * 8)];
  }
}

// ---------------------------------------------------------------------------
// GEMM2: out = Oh[16384x768] @ wprojT^T + bias  (fp32 direct stores)
// 128x256 tile, 512 thr. A,B via global_load_lds; same 2-phase loop.
// ---------------------------------------------------------------------------
__launch_bounds__(512, 3)
__global__ void gemm_proj_kernel(const _Float16* __restrict__ A,
                                 const _Float16* __restrict__ Bt,
                                 const float* __restrict__ bias,
                                 float* __restrict__ out) {
  __shared__ _Float16 sh[24576];       // 2 bufs x (As 4096 + Bs 8192)
  const int tid  = threadIdx.x;
  // XCD swizzle: all 3 column tiles of one m0 on one XCD
  const int lin  = blockIdx.x;         // 384 blocks, 384%8==0 bijective
  const int xcd  = lin & 7, j = lin >> 3;
  const int ct   = j % 3;
  const int m0   = ((j / 3) * 8 + xcd) * 128;
  const int n0   = ct * 256;
  const int w    = tid >> 6, lane = tid & 63;
  const int quad = lane >> 4, l15 = lane & 15;
  const int wr   = w >> 2, wc = w & 3;

  f32x4 acc[4][4] = {};

  // A: granule g = w*64 + lane (512 granules) -> row g>>2, seg g&3
  const _Float16* gaA = A + (size_t)(m0 + ((w * 64 + lane) >> 2)) * 768
                          + (lane & 3) * 8;
  const int ldstA = w * 512;
  // B: granule g = w*128 + c*64 + lane -> row g>>2 (0..255), seg g&3
  const _Float16* gbB = Bt + (size_t)(n0 + ((w * 128 + lane) >> 2)) * 768
                           + (lane & 3) * 8;
  const int ldstB = w * 1024;

  auto STAGE = [&](int buf, int kt) {
    _Float16* As = sh + buf * 12288;
    _Float16* Bs = As + 4096;
    const _Float16* a = gaA + kt * 32;
    const _Float16* b = gbB + kt * 32;
    gld16(a,            As + ldstA);
    gld16(b,            Bs + ldstB);
    gld16(b + 16 * 768, Bs + ldstB + 512);
  };

  STAGE(0, 0);

  for (int kt = 0; kt < 24; ++kt) {
    __syncthreads();
    if (kt < 23) STAGE((kt + 1) & 1, kt + 1);

    const _Float16* As = sh + (kt & 1) * 12288;
    const _Float16* Bs = As + 4096;

    half8 af[4], bf[4];
#pragma unroll
    for (int mi = 0; mi < 4; mi++)
      af[mi] = *(const half8*)&As[(wr * 64 + mi * 16 + l15) * 32 + quad * 8];
#pragma unroll
    for (int ni = 0; ni < 4; ni++)
      bf[ni] = *(const half8*)&Bs[(wc * 64 + ni * 16 + l15) * 32 + quad * 8];
#pragma unroll
    for (int mi = 0; mi < 4; mi++)
#pragma unroll
      for (int ni = 0; ni < 4; ni++)
        acc[mi][ni] = __builtin_amdgcn_mfma_f32_16x16x32_f16(
            af[mi], bf[ni], acc[mi][ni], 0, 0, 0);
  }

  float bcol[4];
#pragma unroll
  for (int ni = 0; ni < 4; ni++)
    bcol[ni] = bias[n0 + wc * 64 + ni * 16 + l15];
#pragma unroll
  for (int mi = 0; mi < 4; mi++)
#pragma unroll
    for (int ni = 0; ni < 4; ni++) {
      int col = n0 + wc * 64 + ni * 16 + l15;
      int row = m0 + wr * 64 + mi * 16 + quad * 4;
#pragma unroll
      for (int r = 0; r < 4; r++)
        out[(size_t)(row + r) * 768 + col] = acc[mi][ni][r] + bcol[ni];
    }
}

// ---------------------------------------------------------------------------
// launch
// ---------------------------------------------------------------------------
extern "C" void kernel_launch(void* const* d_in, const int* in_sizes, int n_in,
                              void* d_out, int out_size, void* d_ws, size_t ws_size,
                              hipStream_t stream) {
  const float* x      = (const float*)d_in[0];
  const float* w_qkv  = (const float*)d_in[1];
  const float* b_qkv  = (const float*)d_in[2];
  const float* w_proj = (const float*)d_in[3];
  const float* b_proj = (const float*)d_in[4];
  float* out = (float*)d_out;

  char* ws = (char*)d_ws;
  _Float16* wqkvT  = (_Float16*)(ws);
  _Float16* wprojT = (_Float16*)(ws + 3538944);
  _Float16* Qp     = (_Float16*)(ws + 4718592);
  _Float16* Kp     = (_Float16*)(ws + 29884416);
  _Float16* VTp    = (_Float16*)(ws + 55050240);
  _Float16* Ohp    = (_Float16*)(ws + 80216064);
  // total: 105381888 B (~100 MB)

  cvt_wt2_kernel<<<dim3(24, 96), 256, 0, stream>>>(w_qkv, wqkvT, w_proj, wprojT);
  gemm_qkv_kernel<<<dim3(1152), 512, 0, stream>>>(x, wqkvT, b_qkv, Qp, Kp, VTp);
  attn_kernel<<<dim3(1536), 256, 0, stream>>>(Qp, Kp, VTp, Ohp);
  gemm_proj_kernel<<<dim3(384), 512, 0, stream>>>(Ohp, wprojT, b_proj, out);
}

// Round 11
// 299.329 us; speedup vs baseline: 1.0310x; 1.0310x over previous
//
#include <hip/hip_runtime.h>

// ---------------------------------------------------------------------------
// Fused MHA block on gfx950, fp16 MFMA pipeline.  (r9 measured-best, 299.5us)
//   qkv GEMM (16384x2304x768, A=fp32 fused-converted) -> per-head flash
//   attention (192 x 1024x1024x64) -> proj GEMM (16384x768x768)
// GEMMs: 128x256 tiles, 8 waves (2Mx4N), v_mfma_f32_16x16x32_f16,
//        2-phase loop, linear LDS, double-buffered, 1 barrier/iter,
//        XCD-swizzled grid. qkv A: fp32->regs->RTN cvt->ds_write (fused
//        cvt_x). qkv B + proj A,B: global_load_lds width-16 direct.
// Ledger (all measured on this problem): (256,{4,5}) launch-bounds regress;
//   A-LDS-bypass 2.3x regress (MFMA frag loads uncoalescable from global);
//   8-phase+counted-vmcnt null; T2-on-GEMM null (conflicts -36x, timing
//   flat); T5/T13 on attn null; attn 32q/wave occupancy rewrite -9us
//   (per-iter amortization loss beats latency-hiding gain).
// Attention: v_mfma_f32_32x32x16_f16 transposed (S^T = K Q^T, O^T = V^T P^T),
//   P in registers via lane^32 half-swap shuffles; 64 q/wave, 256-q blocks.
// ---------------------------------------------------------------------------

typedef _Float16 half8 __attribute__((ext_vector_type(8)));
typedef _Float16 half4 __attribute__((ext_vector_type(4)));
typedef __fp16   fp16x2 __attribute__((ext_vector_type(2)));
typedef float    f32x4  __attribute__((ext_vector_type(4)));
typedef float    f32x16 __attribute__((ext_vector_type(16)));
typedef unsigned int u32x4 __attribute__((ext_vector_type(4)));

#define DI __device__ __forceinline__

constexpr int   BATCH  = 16;
constexpr int   SEQ    = 1024;
constexpr int   DM     = 768;
constexpr int   NH     = 12;
constexpr int   HD     = 64;
constexpr float SCALE  = 0.125f;          // 1/sqrt(64), folded into Q epilogue
constexpr float LOG2E  = 1.4426950408889634f;

DI void copy16(_Float16* dst, const _Float16* src) {
  *(u32x4*)dst = *(const u32x4*)src;
}

DI int pack_rtz(float a, float b) {
  union { fp16x2 h; int i; } u;
  u.h = __builtin_amdgcn_cvt_pkrtz(a, b);
  return u.i;
}

// async global->LDS, 16 B per lane; lds base must be wave-uniform,
// HW writes lane l at lds + l*16.
DI void gld16(const _Float16* g, _Float16* l) {
  __builtin_amdgcn_global_load_lds(
      (const __attribute__((address_space(1))) void*)g,
      (__attribute__((address_space(3))) void*)l, 16, 0, 0);
}

// ---------------------------------------------------------------------------
// converts (weights only; x conversion is fused into gemm_qkv)
// ---------------------------------------------------------------------------
// both weight transposes in one launch: wt[n*K+k] = w[k*N+n]
__global__ void cvt_wt2_kernel(const float* __restrict__ wq,
                               _Float16* __restrict__ wqT,
                               const float* __restrict__ wp,
                               _Float16* __restrict__ wpT) {
  __shared__ float tile[32][33];
  const int by = blockIdx.y;
  const float* w; _Float16* wt; int N, nb;
  if (by < 72) { w = wq; wt = wqT; N = 2304; nb = by * 32; }
  else         { w = wp; wt = wpT; N = 768;  nb = (by - 72) * 32; }
  const int K = 768;
  int kb = blockIdx.x * 32;
  int tx = threadIdx.x & 31, ty = threadIdx.x >> 5;   // ty 0..7
#pragma unroll
  for (int i = 0; i < 32; i += 8)
    tile[ty + i][tx] = w[(size_t)(kb + ty + i) * N + nb + tx];
  __syncthreads();
#pragma unroll
  for (int i = 0; i < 32; i += 8)
    wt[(size_t)(nb + ty + i) * K + kb + tx] = (_Float16)tile[tx][ty + i];
}

// ---------------------------------------------------------------------------
// GEMM1: qkv = x[16384x768 fp32] @ wqkvT^T + bias, scatter epilogue into
//   Q[bh][n][d] (prescaled by 0.125), K[bh][n][d], VT[bh][d][n]  (fp16)
// 128x256 tile, 512 thr (8 waves 2x4). A: fp32->regs->cvt->ds_write.
// B: global_load_lds. LDS/buf: As 4096 h + Bs 8192 h = 24 KB; 2 bufs.
// ---------------------------------------------------------------------------
__launch_bounds__(512, 3)
__global__ void gemm_qkv_kernel(const float* __restrict__ X,
                                const _Float16* __restrict__ Bt,
                                const float* __restrict__ bias,
                                _Float16* __restrict__ Qo,
                                _Float16* __restrict__ Ko,
                                _Float16* __restrict__ VTo) {
  __shared__ _Float16 sh[24576];       // 2 bufs x 12288 halves (49152 B)
  _Float16* Cs = sh;                   // epilogue alias (64*264 = 16896 halves)
  const int tid  = threadIdx.x;
  // XCD swizzle: all 9 column tiles of one m0 land on one XCD (lin&7)
  const int lin  = blockIdx.x;         // 1152 blocks, 1152%8==0 bijective
  const int xcd  = lin & 7, j = lin >> 3;
  const int ct   = j % 9;              // 0..8 col tiles of 256
  const int m0   = ((j / 9) * 8 + xcd) * 128;
  const int n0   = ct * 256;
  const int w    = tid >> 6, lane = tid & 63;
  const int quad = lane >> 4, l15 = lane & 15;
  const int wr   = w >> 2, wc = w & 3; // 2 row-waves x 4 col-waves

  f32x4 acc[4][4] = {};

  // ---- A staging geometry (512 thr, one granule each): row tid>>2, seg tid&3
  const int rA = tid >> 2, sA = tid & 3;
  const float* gaA = X + (size_t)(m0 + rA) * 768 + sA * 8;
  const int so = rA * 32 + sA * 8;     // linear [128][32] dest (halves)

  // ---- B staging (gld_lds): granule g = w*128 + c*64 + lane (c = call 0/1)
  //      row g>>2 (0..255), seg g&3; dest = g*8 halves.
  const _Float16* gbB = Bt + (size_t)(n0 + ((w * 128 + lane) >> 2)) * 768
                           + (lane & 3) * 8;
  const int ldst = w * 1024;           // B dest halves, call 0 (call 1: +512)

  auto CVT_WRITE = [&](float4 a0, float4 a1, _Float16* As) {
    half8 h0;
    h0[0] = (_Float16)a0.x; h0[1] = (_Float16)a0.y;
    h0[2] = (_Float16)a0.z; h0[3] = (_Float16)a0.w;
    h0[4] = (_Float16)a1.x; h0[5] = (_Float16)a1.y;
    h0[6] = (_Float16)a1.z; h0[7] = (_Float16)a1.w;
    *(half8*)(As + so) = h0;
  };

  // prologue: tile 0 -> buf 0  (As at 0, Bs at 4096)
  {
    float4 a0 = *(const float4*)(gaA);
    float4 a1 = *(const float4*)(gaA + 4);
    CVT_WRITE(a0, a1, sh);
    gld16(gbB,            sh + 4096 + ldst);
    gld16(gbB + 16 * 768, sh + 4096 + ldst + 512);
  }

  for (int kt = 0; kt < 24; ++kt) {
    __syncthreads();                   // drains vm (B) + lgkm (A writes)
    float4 a0, a1;
    if (kt < 23) {                     // prefetch next tile
      const int k0 = (kt + 1) * 32;
      a0 = *(const float4*)(gaA + k0);
      a1 = *(const float4*)(gaA + k0 + 4);
      _Float16* Bsn = sh + ((kt + 1) & 1) * 12288 + 4096;
      gld16(gbB + k0,            Bsn + ldst);
      gld16(gbB + k0 + 16 * 768, Bsn + ldst + 512);
    }

    const _Float16* As = sh + (kt & 1) * 12288;
    const _Float16* Bs = As + 4096;

    half8 af[4], bf[4];
#pragma unroll
    for (int mi = 0; mi < 4; mi++)
      af[mi] = *(const half8*)&As[(wr * 64 + mi * 16 + l15) * 32 + quad * 8];
#pragma unroll
    for (int ni = 0; ni < 4; ni++)
      bf[ni] = *(const half8*)&Bs[(wc * 64 + ni * 16 + l15) * 32 + quad * 8];
#pragma unroll
    for (int mi = 0; mi < 4; mi++)
#pragma unroll
      for (int ni = 0; ni < 4; ni++)
        acc[mi][ni] = __builtin_amdgcn_mfma_f32_16x16x32_f16(
            af[mi], bf[ni], acc[mi][ni], 0, 0, 0);

    if (kt < 23)                       // stage converted A into other buf
      CVT_WRITE(a0, a1, sh + ((kt + 1) & 1) * 12288);
  }
  __syncthreads();

  const int   sec    = ct / 3;         // 0=Q 1=K 2=V
  const int   h0     = (ct % 3) * 4;   // 4 heads per 256-col tile
  const float oscale = (sec == 0) ? SCALE : 1.0f;
  float bcol[4];
#pragma unroll
  for (int ni = 0; ni < 4; ni++)
    bcol[ni] = bias[n0 + wc * 64 + ni * 16 + l15];

  const int b     = m0 >> 10;
  const int nrow0 = m0 & 1023;

  // two passes of 64 rows each through Cs[64][264]
#pragma unroll
  for (int p = 0; p < 2; ++p) {
    if (p) __syncthreads();            // pass-0 reads done before overwrite
    if (wr == p) {
#pragma unroll
      for (int mi = 0; mi < 4; mi++)
#pragma unroll
        for (int ni = 0; ni < 4; ni++) {
          int col = wc * 64 + ni * 16 + l15;
          int row = mi * 16 + quad * 4;
#pragma unroll
          for (int r = 0; r < 4; r++)
            Cs[(row + r) * 264 + col] =
                (_Float16)((acc[mi][ni][r] + bcol[ni]) * oscale);
        }
    }
    __syncthreads();

    if (sec < 2) {
      _Float16* dst = (sec == 0) ? Qo : Ko;
      int row = tid >> 3, seg = tid & 7;     // 64 rows x 8 segs of 32
      int hl = seg >> 1, off32 = (seg & 1) * 32;
      _Float16* g = dst +
          ((size_t)((b * NH + h0 + hl) * SEQ + nrow0 + p * 64 + row)) * HD + off32;
      const _Float16* s = &Cs[row * 264 + hl * 64 + off32];
      copy16(g, s);
      copy16(g + 8, s + 8);
      copy16(g + 16, s + 16);
      copy16(g + 24, s + 24);
    } else {
      int c = tid & 255, rh = tid >> 8;      // col, row half (32 rows each)
      int hl = c >> 6, d = c & 63;
      _Float16 tmp[32];
#pragma unroll
      for (int jj = 0; jj < 32; jj++) tmp[jj] = Cs[(rh * 32 + jj) * 264 + c];
      _Float16* g = VTo + ((size_t)((b * NH + h0 + hl) * HD + d)) * SEQ
                        + nrow0 + p * 64 + rh * 32;
#pragma unroll
      for (int jj = 0; jj < 4; jj++)
        copy16(g + jj * 8, (const _Float16*)&tmp[jj * 8]);
    }
  }
}

// ---------------------------------------------------------------------------
// Flash attention, transposed: one wg = (bh, 256-q tile), 4 waves x 64 q.
// S^T = K Q^T (32x32x16 MFMA), P^T kept in registers via half-swap shuffles,
// O^T = V^T P^T.  K-tile 64, double-buffered LDS staging.
// ---------------------------------------------------------------------------
__launch_bounds__(256, 2)
__global__ void attn_kernel(const _Float16* __restrict__ Q,
                            const _Float16* __restrict__ K,
                            const _Float16* __restrict__ VT,
                            _Float16* __restrict__ Oh) {
  __shared__ _Float16 smem[2][2][64 * 72];   // [buf][K/V][64 rows][72]
  _Float16* OLds = &smem[0][0][0];           // aliased epilogue staging (36864B)

  const int tid = threadIdx.x;
  const int i   = blockIdx.x;
  const int bh  = (i & 7) * 24 + ((i >> 3) >> 2);   // XCD swizzle: 4 q-blocks
  const int q0  = ((i >> 3) & 3) * 256;             //  of one bh share an XCD
  const int b   = bh / NH, hh = bh - b * NH;
  const int w   = tid >> 6, lane = tid & 63;
  const int l31 = lane & 31, h = lane >> 5;

  const _Float16* Qg = Q  + (size_t)bh * SEQ * HD;
  const _Float16* Kg = K  + (size_t)bh * SEQ * HD;
  const _Float16* Vg = VT + (size_t)bh * HD * SEQ;

  // persistent Q B-frags: qb[N][s] ; B[k=d][n=q] read from Q[q][d] row-major
  half8 qb[2][4];
#pragma unroll
  for (int N = 0; N < 2; N++) {
    const _Float16* qrow = Qg + (size_t)(q0 + w * 64 + N * 32 + l31) * HD + h * 8;
#pragma unroll
    for (int s = 0; s < 4; s++)
      qb[N][s] = *(const half8*)(qrow + s * 16);
  }

  // staging: threads 0-127 stage K tile, 128-255 stage V^T tile (64B each)
  const int  sr  = (tid & 127) >> 1;
  const int  sp  = tid & 1;
  const bool isK = tid < 128;
  const _Float16* sg = isK ? (Kg + sr * HD + sp * 32)
                           : (Vg + (size_t)sr * SEQ + sp * 32);
  const int sstep = isK ? 64 * HD : 64;
  const int soff  = (isK ? 0 : 64 * 72) + sr * 72 + sp * 32;

  u32x4 pf[4];
#pragma unroll
  for (int c = 0; c < 4; c++) pf[c] = *(const u32x4*)(sg + c * 8);
#pragma unroll
  for (int c = 0; c < 4; c++) *(u32x4*)(&smem[0][0][0] + soff + c * 8) = pf[c];

  f32x16 of[2][2];
#pragma unroll
  for (int D = 0; D < 2; D++)
#pragma unroll
    for (int N = 0; N < 2; N++)
#pragma unroll
      for (int r = 0; r < 16; r++) of[D][N][r] = 0.f;
  float m_[2] = {-1e30f, -1e30f}, l_[2] = {0.f, 0.f};

  for (int kt = 0; kt < 16; ++kt) {
    if (kt < 15) {
      const _Float16* nsg = sg + (kt + 1) * sstep;
#pragma unroll
      for (int c = 0; c < 4; c++) pf[c] = *(const u32x4*)(nsg + c * 8);
    }
    __syncthreads();
    const _Float16* Ks = &smem[kt & 1][0][0];
    const _Float16* Vs = &smem[kt & 1][1][0];

    // S^T = K Q^T : 2 m-frags (64 keys) x 2 n-frags (64 q)
    f32x16 sf[2][2];
#pragma unroll
    for (int M = 0; M < 2; M++)
#pragma unroll
      for (int N = 0; N < 2; N++)
#pragma unroll
        for (int r = 0; r < 16; r++) sf[M][N][r] = 0.f;
#pragma unroll
    for (int s = 0; s < 4; s++) {
      half8 ka0 = *(const half8*)&Ks[l31 * 72 + s * 16 + h * 8];
      half8 ka1 = *(const half8*)&Ks[(32 + l31) * 72 + s * 16 + h * 8];
#pragma unroll
      for (int N = 0; N < 2; N++) {
        sf[0][N] = __builtin_amdgcn_mfma_f32_32x32x16_f16(ka0, qb[N][s], sf[0][N], 0, 0, 0);
        sf[1][N] = __builtin_amdgcn_mfma_f32_32x32x16_f16(ka1, qb[N][s], sf[1][N], 0, 0, 0);
      }
    }

    // online softmax; stats are per q = per lane (col of S^T)
    float alpha[2], c1[2], tsum[2];
#pragma unroll
    for (int N = 0; N < 2; N++) {
      float tmax = -1e30f;
#pragma unroll
      for (int r = 0; r < 16; r++)
        tmax = fmaxf(tmax, fmaxf(sf[0][N][r], sf[1][N][r]));
      tmax = fmaxf(tmax, __shfl_xor(tmax, 32, 64));
      float mnew = fmaxf(m_[N], tmax);
      alpha[N] = __builtin_amdgcn_exp2f((m_[N] - mnew) * LOG2E);
      m_[N] = mnew;
      c1[N] = mnew * LOG2E;
      tsum[N] = 0.f;
    }

    // exp -> P^T, pack fp16 pairs into dwords (kept in registers)
    int pdw[2][2][8];
#pragma unroll
    for (int M = 0; M < 2; M++)
#pragma unroll
      for (int N = 0; N < 2; N++) {
#pragma unroll
        for (int r = 0; r < 16; r++) {
          float p = __builtin_amdgcn_exp2f(sf[M][N][r] * LOG2E - c1[N]);
          sf[M][N][r] = p;
          tsum[N] += p;
        }
#pragma unroll
        for (int u = 0; u < 8; u++)
          pdw[M][N][u] = pack_rtz(sf[M][N][2 * u], sf[M][N][2 * u + 1]);
      }
#pragma unroll
    for (int N = 0; N < 2; N++) {
      tsum[N] += __shfl_xor(tsum[N], 32, 64);
      l_[N] = l_[N] * alpha[N] + tsum[N];
    }
#pragma unroll
    for (int D = 0; D < 2; D++)
#pragma unroll
      for (int N = 0; N < 2; N++)
#pragma unroll
        for (int r = 0; r < 16; r++) of[D][N][r] *= alpha[N];

    // O^T += V^T P^T ; P^T B-frags assembled from pdw via lane^32 half-swap
#pragma unroll
    for (int t = 0; t < 4; ++t) {
      const int M = t >> 1, s2 = (t & 1) * 4;
      half8 va0 = *(const half8*)&Vs[l31 * 72 + t * 16 + h * 8];
      half8 va1 = *(const half8*)&Vs[(32 + l31) * 72 + t * 16 + h * 8];
#pragma unroll
      for (int N = 0; N < 2; N++) {
        int a0 = pdw[M][N][s2 + 0], a1 = pdw[M][N][s2 + 1];
        int a2 = pdw[M][N][s2 + 2], a3 = pdw[M][N][s2 + 3];
        int e0 = h ? a0 : a2, e1 = h ? a1 : a3;
        int r0 = __shfl_xor(e0, 32, 64), r1 = __shfl_xor(e1, 32, 64);
        union { u32x4 u; half8 hv; } bb;
        bb.u[0] = h ? r0 : a0; bb.u[1] = h ? r1 : a1;
        bb.u[2] = h ? a2 : r0; bb.u[3] = h ? a3 : r1;
        of[0][N] = __builtin_amdgcn_mfma_f32_32x32x16_f16(va0, bb.hv, of[0][N], 0, 0, 0);
        of[1][N] = __builtin_amdgcn_mfma_f32_32x32x16_f16(va1, bb.hv, of[1][N], 0, 0, 0);
      }
    }

    if (kt < 15) {
      _Float16* dst = &smem[(kt + 1) & 1][0][0] + soff;
#pragma unroll
      for (int c = 0; c < 4; c++) *(u32x4*)(dst + c * 8) = pf[c];
    }
  }

  // epilogue: normalize, transpose O^T -> O through LDS, coalesced store
  __syncthreads();                       // all waves done with staging buffers
  float inv[2] = {1.0f / l_[0], 1.0f / l_[1]};
  int* OW = (int*)OLds;
#pragma unroll
  for (int N = 0; N < 2; N++) {
    const int q_local = w * 64 + N * 32 + l31;
#pragma unroll
    for (int D = 0; D < 2; D++)
#pragma unroll
      for (int u = 0; u < 8; u++) {
        int v = pack_rtz(of[D][N][2 * u] * inv[N], of[D][N][2 * u + 1] * inv[N]);
        int dwi = 16 * D + 4 * (u >> 1) + (u & 1) + 2 * h;
        OW[q_local * 36 + dwi] = v;
      }
  }
  __syncthreads();
#pragma unroll
  for (int p = 0; p < 8; p++) {
    int q = p * 32 + (tid >> 3), c = tid & 7;
    *(u32x4*)(Oh + (size_t)(b * SEQ + q0 + q) * DM + hh * HD + c * 8) =
        *(const u32x4*)&OLds[q * 72 + c * 8];
  }
}

// ---------------------------------------------------------------------------
// GEMM2: out = Oh[16384x768] @ wprojT^T + bias  (fp32 direct stores)
// 128x256 tile, 512 thr. A,B via global_load_lds; same 2-phase loop.
// ---------------------------------------------------------------------------
__launch_bounds__(512, 3)
__global__ void gemm_proj_kernel(const _Float16* __restrict__ A,
                                 const _Float16* __restrict__ Bt,
                                 const float* __restrict__ bias,
                                 float* __restrict__ out) {
  __shared__ _Float16 sh[24576];       // 2 bufs x (As 4096 + Bs 8192)
  const int tid  = threadIdx.x;
  // XCD swizzle: all 3 column tiles of one m0 on one XCD
  const int lin  = blockIdx.x;         // 384 blocks, 384%8==0 bijective
  const int xcd  = lin & 7, j = lin >> 3;
  const int ct   = j % 3;
  const int m0   = ((j / 3) * 8 + xcd) * 128;
  const int n0   = ct * 256;
  const int w    = tid >> 6, lane = tid & 63;
  const int quad = lane >> 4, l15 = lane & 15;
  const int wr   = w >> 2, wc = w & 3;

  f32x4 acc[4][4] = {};

  // A: granule g = w*64 + lane (512 granules) -> row g>>2, seg g&3
  const _Float16* gaA = A + (size_t)(m0 + ((w * 64 + lane) >> 2)) * 768
                          + (lane & 3) * 8;
  const int ldstA = w * 512;
  // B: granule g = w*128 + c*64 + lane -> row g>>2 (0..255), seg g&3
  const _Float16* gbB = Bt + (size_t)(n0 + ((w * 128 + lane) >> 2)) * 768
                           + (lane & 3) * 8;
  const int ldstB = w * 1024;

  auto STAGE = [&](int buf, int kt) {
    _Float16* As = sh + buf * 12288;
    _Float16* Bs = As + 4096;
    const _Float16* a = gaA + kt * 32;
    const _Float16* b = gbB + kt * 32;
    gld16(a,            As + ldstA);
    gld16(b,            Bs + ldstB);
    gld16(b + 16 * 768, Bs + ldstB + 512);
  };

  STAGE(0, 0);

  for (int kt = 0; kt < 24; ++kt) {
    __syncthreads();
    if (kt < 23) STAGE((kt + 1) & 1, kt + 1);

    const _Float16* As = sh + (kt & 1) * 12288;
    const _Float16* Bs = As + 4096;

    half8 af[4], bf[4];
#pragma unroll
    for (int mi = 0; mi < 4; mi++)
      af[mi] = *(const half8*)&As[(wr * 64 + mi * 16 + l15) * 32 + quad * 8];
#pragma unroll
    for (int ni = 0; ni < 4; ni++)
      bf[ni] = *(const half8*)&Bs[(wc * 64 + ni * 16 + l15) * 32 + quad * 8];
#pragma unroll
    for (int mi = 0; mi < 4; mi++)
#pragma unroll
      for (int ni = 0; ni < 4; ni++)
        acc[mi][ni] = __builtin_amdgcn_mfma_f32_16x16x32_f16(
            af[mi], bf[ni], acc[mi][ni], 0, 0, 0);
  }

  float bcol[4];
#pragma unroll
  for (int ni = 0; ni < 4; ni++)
    bcol[ni] = bias[n0 + wc * 64 + ni * 16 + l15];
#pragma unroll
  for (int mi = 0; mi < 4; mi++)
#pragma unroll
    for (int ni = 0; ni < 4; ni++) {
      int col = n0 + wc * 64 + ni * 16 + l15;
      int row = m0 + wr * 64 + mi * 16 + quad * 4;
#pragma unroll
      for (int r = 0; r < 4; r++)
        out[(size_t)(row + r) * 768 + col] = acc[mi][ni][r] + bcol[ni];
    }
}

// ---------------------------------------------------------------------------
// launch
// ---------------------------------------------------------------------------
extern "C" void kernel_launch(void* const* d_in, const int* in_sizes, int n_in,
                              void* d_out, int out_size, void* d_ws, size_t ws_size,
                              hipStream_t stream) {
  const float* x      = (const float*)d_in[0];
  const float* w_qkv  = (const float*)d_in[1];
  const float* b_qkv  = (const float*)d_in[2];
  const float* w_proj = (const float*)d_in[3];
  const float* b_proj = (const float*)d_in[4];
  float* out = (float*)d_out;

  char* ws = (char*)d_ws;
  _Float16* wqkvT  = (_Float16*)(ws);
  _Float16* wprojT = (_Float16*)(ws + 3538944);
  _Float16* Qp     = (_Float16*)(ws + 4718592);
  _Float16* Kp     = (_Float16*)(ws + 29884416);
  _Float16* VTp    = (_Float16*)(ws + 55050240);
  _Float16* Ohp    = (_Float16*)(ws + 80216064);
  // total: 105381888 B (~100 MB)

  cvt_wt2_kernel<<<dim3(24, 96), 256, 0, stream>>>(w_qkv, wqkvT, w_proj, wprojT);
  gemm_qkv_kernel<<<dim3(1152), 512, 0, stream>>>(x, wqkvT, b_qkv, Qp, Kp, VTp);
  attn_kernel<<<dim3(768), 256, 0, stream>>>(Qp, Kp, VTp, Ohp);
  gemm_proj_kernel<<<dim3(384), 512, 0, stream>>>(Ohp, wprojT, b_proj, out);
}